// Round 4
// baseline (268.435 us; speedup 1.0000x reference)
//
#include <hip/hip_runtime.h>
#include <hip/hip_bf16.h>
#include <stdint.h>

typedef short short8 __attribute__((ext_vector_type(8)));
typedef float f32x4 __attribute__((ext_vector_type(4)));

// Problem constants
constexpr int SEQ   = 2048;   // T
constexpr int DM    = 1024;   // model dim
constexpr int NHEAD = 16;
constexpr int HD    = 64;     // head dim
constexpr int LDQ   = 1152;   // QKV row stride: 1024 Q | 64 K | 64 V
constexpr int BATCH = 2;

__device__ __forceinline__ unsigned short f2bf(float f) {
    union { float f; uint32_t u; } v; v.f = f;
    uint32_t u = v.u;
    uint32_t r = (u + 0x7fffu + ((u >> 16) & 1u)) >> 16;
    return (unsigned short)r;
}

// async global->LDS, 16B per lane. LDS dest = wave-uniform base + lane*16.
typedef __attribute__((address_space(1))) const void gvoid_t;
typedef __attribute__((address_space(3))) void lvoid_t;
__device__ __forceinline__ void gload16(const void* g, void* l) {
    __builtin_amdgcn_global_load_lds((gvoid_t*)g, (lvoid_t*)l, 16, 0, 0);
}

// ---------------- cast x (fp32 -> bf16), vectorized ----------------
__global__ __launch_bounds__(256) void cast_x_kernel(
        const float* __restrict__ x, unsigned short* __restrict__ xb, int n) {
    int i = (blockIdx.x * 256 + threadIdx.x) * 4;
    if (i >= n) return;
    const float4 v = *(const float4*)(x + i);
    ushort4 o;
    o.x = f2bf(v.x); o.y = f2bf(v.y); o.z = f2bf(v.z); o.w = f2bf(v.w);
    *(ushort4*)(xb + i) = o;
}

// ---- fused weight prep: cast+transpose Wq,Wk,Wv,Wo in one launch ----
__global__ __launch_bounds__(256) void prep_w_kernel(
        const float* __restrict__ Wq, const float* __restrict__ Wk,
        const float* __restrict__ Wv, const float* __restrict__ Wo,
        unsigned short* __restrict__ wtq, unsigned short* __restrict__ wot) {
    __shared__ unsigned short tile[32][33];
    int z = blockIdx.z;
    const float* W; unsigned short* Wt; int C;
    if (z == 0)      { W = Wq; Wt = wtq;                              C = DM; }
    else if (z == 1) { W = Wk; Wt = wtq + (size_t)DM * DM;            C = HD; }
    else if (z == 2) { W = Wv; Wt = wtq + (size_t)(DM + HD) * DM;     C = HD; }
    else             { W = Wo; Wt = wot;                              C = DM; }
    int c0 = blockIdx.x * 32, r0 = blockIdx.y * 32;
    if (c0 >= C) return;
    int tx = threadIdx.x & 31, ty = threadIdx.x >> 5;  // ty 0..7
    for (int i = ty; i < 32; i += 8)
        tile[i][tx] = f2bf(W[(size_t)(r0 + i) * C + (c0 + tx)]);
    __syncthreads();
    for (int i = ty; i < 32; i += 8)
        Wt[(size_t)(c0 + i) * DM + (r0 + tx)] = tile[tx][i];
}

// ------- transpose V slice of QKV (bf16 [seq][hd] -> Vt [hd][seq]) -------
__global__ __launch_bounds__(256) void transpose_v_kernel(
        const unsigned short* __restrict__ QKV, unsigned short* __restrict__ Vt) {
    __shared__ unsigned short tile[32][33];
    int b = blockIdx.z;
    int s0 = blockIdx.x * 32;   // seq
    int d0 = blockIdx.y * 32;   // head-dim
    int tx = threadIdx.x & 31, ty = threadIdx.x >> 5;
    const unsigned short* src = QKV + (size_t)b * SEQ * LDQ + DM + HD;
    for (int i = ty; i < 32; i += 8)
        tile[i][tx] = src[(size_t)(s0 + i) * LDQ + d0 + tx];
    __syncthreads();
    unsigned short* dst = Vt + (size_t)b * HD * SEQ;
    for (int i = ty; i < 32; i += 8)
        dst[(size_t)(d0 + i) * SEQ + s0 + tx] = tile[tx][i];
}

// ------------- GEMM: C[M,N] = A[M,K](bf16) @ Bt[N,K]^T(bf16) -------------
// 128x64 tile, BK=64 as two unpadded 128x32 half-tiles (gload16-compatible),
// 6 gload16 + 16 MFMA per wave per barrier-pair. 4 waves in 2x2, each wave
// 64x32 of output via 4x2 of mfma_f32_16x16x32_bf16 per k-half.
__global__ __launch_bounds__(256) void gemm_bt_kernel(
        const unsigned short* __restrict__ A,
        const unsigned short* __restrict__ Bt,
        void* __restrict__ Cout,
        int M, int N, int K, int out_bf16) {
    __shared__ unsigned short ldsA[2][128 * 32];
    __shared__ unsigned short ldsB[2][64 * 32];
    int lane = threadIdx.x & 63, wave = threadIdx.x >> 6;
    int ln = lane & 15, quad = lane >> 4;
    int wm = wave >> 1, wn = wave & 1;
    int m0 = blockIdx.y * 128, n0 = blockIdx.x * 64;

    // staging: one gload16 covers 16 rows x 32 cols (lane>>2 = row, (lane&3)*8 = col)
    int srow = lane >> 2, scol = (lane & 3) * 8;
    const unsigned short* gA0 = A + (size_t)(m0 + wave * 32 + srow) * K + scol;
    const unsigned short* gA1 = gA0 + (size_t)16 * K;
    const unsigned short* gB0 = Bt + (size_t)(n0 + wave * 16 + srow) * K + scol;

    f32x4 acc[4][2];
    for (int i = 0; i < 4; ++i)
        for (int jj = 0; jj < 2; ++jj) acc[i][jj] = f32x4{0, 0, 0, 0};

    for (int k0 = 0; k0 < K; k0 += 64) {
#pragma unroll
        for (int hh = 0; hh < 2; ++hh) {
            gload16(gA0 + k0 + hh * 32, &ldsA[hh][wave * 1024]);
            gload16(gA1 + k0 + hh * 32, &ldsA[hh][wave * 1024 + 512]);
            gload16(gB0 + k0 + hh * 32, &ldsB[hh][wave * 512]);
        }
        __syncthreads();
        short8 aF[2][4], bF[2][2];
#pragma unroll
        for (int hh = 0; hh < 2; ++hh) {
#pragma unroll
            for (int i = 0; i < 4; ++i)
                aF[hh][i] = *(const short8*)&ldsA[hh][(wm * 64 + i * 16 + ln) * 32 + quad * 8];
#pragma unroll
            for (int jj = 0; jj < 2; ++jj)
                bF[hh][jj] = *(const short8*)&ldsB[hh][(wn * 32 + jj * 16 + ln) * 32 + quad * 8];
        }
#pragma unroll
        for (int hh = 0; hh < 2; ++hh)
#pragma unroll
            for (int mt = 0; mt < 4; ++mt)
#pragma unroll
                for (int nt = 0; nt < 2; ++nt)
                    acc[mt][nt] = __builtin_amdgcn_mfma_f32_16x16x32_bf16(
                        aF[hh][mt], bF[hh][nt], acc[mt][nt], 0, 0, 0);
        __syncthreads();
    }

    if (out_bf16) {
        unsigned short* C = (unsigned short*)Cout;
#pragma unroll
        for (int mt = 0; mt < 4; ++mt)
            for (int nt = 0; nt < 2; ++nt)
                for (int r = 0; r < 4; ++r) {
                    int row = m0 + wm * 64 + mt * 16 + quad * 4 + r;
                    int col = n0 + wn * 32 + nt * 16 + ln;
                    C[(size_t)row * N + col] = f2bf(acc[mt][nt][r]);
                }
    } else {
        float* C = (float*)Cout;
#pragma unroll
        for (int mt = 0; mt < 4; ++mt)
            for (int nt = 0; nt < 2; ++nt)
                for (int r = 0; r < 4; ++r) {
                    int row = m0 + wm * 64 + mt * 16 + quad * 4 + r;
                    int col = n0 + wn * 32 + nt * 16 + ln;
                    C[(size_t)row * N + col] = acc[mt][nt][r];
                }
    }
}

// ---------------- flash attention (multi-query, causal) ----------------
// Constant-max streaming softmax (scores bounded; exp cannot overflow):
// partials combine by plain addition, enabling 2-way split-K:
//   block = 2 q-tile-pairs x 2 key-splits (step parity). Each wave computes
//   partial (O, l) over its parity's 32-key steps; split-1 publishes via LDS,
//   split-0 merges and writes Y. Grid 1024 blocks = 4/CU = 16 waves/CU.
// Mirrored pair (j, 127-j) keeps per-wave work uniform (~32 steps each).
__global__ __launch_bounds__(256) void attn_kernel(
        const unsigned short* __restrict__ QKV,
        const unsigned short* __restrict__ Vt,
        unsigned short* __restrict__ Y) {
    __shared__ unsigned short pbuf[4][2][16][40];  // per-wave P round-trip
    __shared__ float cbuf[2][2][16][68];           // [pairIdx][t][row][col] partial O
    __shared__ float lbuf[2][2][16];               // partial l
    int lane = threadIdx.x & 63, wave = threadIdx.x >> 6;
    int ln = lane & 15, quad = lane >> 4;
    int pi = wave >> 1, split = wave & 1;
    int pair = blockIdx.x * 2 + pi;       // 0..2047
    int j  = pair & 63;                   // tile-pair index
    int bh = pair >> 6;                   // 0..31
    int h  = bh & 15, b = bh >> 4;
    const int q0[2] = { j * 16, (127 - j) * 16 };
    const size_t baseRow = (size_t)b * SEQ;
    const unsigned short* Vb = Vt + (size_t)b * HD * SEQ;

    short8 aQ[2][2];
#pragma unroll
    for (int t = 0; t < 2; ++t) {
        const unsigned short* qp = QKV + (baseRow + q0[t] + ln) * LDQ + h * HD + quad * 8;
        aQ[t][0] = *(const short8*)(qp);
        aQ[t][1] = *(const short8*)(qp + 32);
    }

    float lsum[2][4];
    f32x4 o[2][4];
#pragma unroll
    for (int t = 0; t < 2; ++t) {
        for (int r = 0; r < 4; ++r) lsum[t][r] = 0.f;
        for (int nt = 0; nt < 4; ++nt) o[t][nt] = f32x4{0, 0, 0, 0};
    }

    // exp(s/8) = exp2(s * 0.125 * log2(e))
    const float c_exp = 0.1803368802f;

    const int smax1 = q0[1] + 15;
    for (int s0 = split * 32; s0 <= smax1; s0 += 64) {
        // shared K fragments: B-layout, n=key=ln, k=hd
        short8 bK[2][2];
#pragma unroll
        for (int c = 0; c < 2; ++c) {
            const unsigned short* kp = QKV + (baseRow + s0 + c * 16 + ln) * LDQ + DM + quad * 8;
            bK[c][0] = *(const short8*)(kp);
            bK[c][1] = *(const short8*)(kp + 32);
        }
        // shared V fragments: B-layout, n=hd=ln, k=key (contiguous in Vt)
        short8 bV[4];
#pragma unroll
        for (int nt = 0; nt < 4; ++nt)
            bV[nt] = *(const short8*)(Vb + (size_t)(nt * 16 + ln) * SEQ + s0 + quad * 8);

#pragma unroll
        for (int t = 0; t < 2; ++t) {
            if (s0 > q0[t] + 15) continue;  // wave-uniform
            float p[2][4];
#pragma unroll
            for (int c = 0; c < 2; ++c) {
                f32x4 s = {0, 0, 0, 0};
                s = __builtin_amdgcn_mfma_f32_16x16x32_bf16(aQ[t][0], bK[c][0], s, 0, 0, 0);
                s = __builtin_amdgcn_mfma_f32_16x16x32_bf16(aQ[t][1], bK[c][1], s, 0, 0, 0);
                int srow = s0 + c * 16 + ln;
                for (int r = 0; r < 4; ++r) {
                    int ti = q0[t] + quad * 4 + r;
                    float e = __builtin_exp2f(s[r] * c_exp);
                    p[c][r] = (srow > ti) ? 0.f : e;   // causal mask
                }
            }
#pragma unroll
            for (int r = 0; r < 4; ++r) lsum[t][r] += p[0][r] + p[1][r];

            // P: C-layout -> LDS -> A-layout (per-wave private, no barrier)
#pragma unroll
            for (int c = 0; c < 2; ++c)
                for (int r = 0; r < 4; ++r)
                    pbuf[wave][t][quad * 4 + r][c * 16 + ln] = f2bf(p[c][r]);
            short8 aP = *(const short8*)&pbuf[wave][t][ln][quad * 8];
#pragma unroll
            for (int nt = 0; nt < 4; ++nt)
                o[t][nt] = __builtin_amdgcn_mfma_f32_16x16x32_bf16(aP, bV[nt], o[t][nt], 0, 0, 0);
        }
    }

    // reduce l across the 16 lanes of each quad (all lanes end with the sum)
#pragma unroll
    for (int t = 0; t < 2; ++t)
        for (int off = 1; off < 16; off <<= 1)
#pragma unroll
            for (int r = 0; r < 4; ++r) lsum[t][r] += __shfl_xor(lsum[t][r], off);

    // split-1 publishes partials
    if (split == 1) {
#pragma unroll
        for (int t = 0; t < 2; ++t) {
            for (int nt = 0; nt < 4; ++nt)
                for (int r = 0; r < 4; ++r)
                    cbuf[pi][t][quad * 4 + r][nt * 16 + ln] = o[t][nt][r];
            if (ln == 0)
                for (int r = 0; r < 4; ++r) lbuf[pi][t][quad * 4 + r] = lsum[t][r];
        }
    }
    __syncthreads();
    // split-0 merges and writes Y
    if (split == 0) {
#pragma unroll
        for (int t = 0; t < 2; ++t)
            for (int r = 0; r < 4; ++r) {
                float l = lsum[t][r] + lbuf[pi][t][quad * 4 + r];
                float inv = 1.0f / l;
                int t_idx = q0[t] + quad * 4 + r;
                unsigned short* yp = Y + (baseRow + t_idx) * DM + h * HD + ln;
                for (int nt = 0; nt < 4; ++nt) {
                    float ov = o[t][nt][r] + cbuf[pi][t][quad * 4 + r][nt * 16 + ln];
                    yp[nt * 16] = f2bf(ov * inv);
                }
            }
    }
}

extern "C" void kernel_launch(void* const* d_in, const int* in_sizes, int n_in,
                              void* d_out, int out_size, void* d_ws, size_t ws_size,
                              hipStream_t stream) {
    const float* x  = (const float*)d_in[0];
    const float* Wq = (const float*)d_in[1];
    const float* Wk = (const float*)d_in[2];
    const float* Wv = (const float*)d_in[3];
    const float* Wo = (const float*)d_in[4];
    float* out = (float*)d_out;

    char* ws = (char*)d_ws;
    // workspace layout; Vt aliases xb (xb is dead after the QKV GEMM)
    unsigned short* xb  = (unsigned short*)(ws);                // 4096x1024 bf16  (8 MB)
    unsigned short* Vt  = (unsigned short*)(ws);                // 2x64x2048 bf16  (alias)
    unsigned short* wtq = (unsigned short*)(ws + 8388608);      // 1152x1024 bf16: Wq^T|Wk^T|Wv^T
    unsigned short* wot = (unsigned short*)(ws + 10747904);     // 1024x1024 bf16  (Wo^T)
    unsigned short* qkv = (unsigned short*)(ws + 12845056);     // 4096x1152 bf16
    unsigned short* y   = (unsigned short*)(ws + 22282240);     // 4096x1024 bf16

    const int BT = BATCH * SEQ;  // 4096 rows

    hipLaunchKernelGGL(cast_x_kernel, dim3(BT * DM / 4 / 256), dim3(256), 0, stream,
                       x, xb, BT * DM);
    hipLaunchKernelGGL(prep_w_kernel, dim3(DM / 32, DM / 32, 4), dim3(256), 0, stream,
                       Wq, Wk, Wv, Wo, wtq, wot);

    // QKV = x @ [Wq|Wk|Wv]  -> bf16   (576 blocks)
    hipLaunchKernelGGL(gemm_bt_kernel, dim3(LDQ / 64, BT / 128), dim3(256), 0, stream,
                       xb, wtq, (void*)qkv, BT, LDQ, DM, 1);

    // V -> Vt [b][hd][seq]   (xb dead from here; Vt aliases it)
    hipLaunchKernelGGL(transpose_v_kernel, dim3(SEQ / 32, HD / 32, BATCH), dim3(256), 0, stream,
                       qkv, Vt);

    // flash attention (split-K over step parity) -> Y bf16   (1024 blocks)
    hipLaunchKernelGGL(attn_kernel, dim3(BATCH * NHEAD * 64 / 2), dim3(256), 0, stream,
                       qkv, Vt, y);

    // out = Y @ Wo -> fp32   (512 blocks)
    hipLaunchKernelGGL(gemm_bt_kernel, dim3(DM / 64, BT / 128), dim3(256), 0, stream,
                       y, wot, (void*)out, BT, DM, DM, 0);
}

// Round 5
// 187.573 us; speedup vs baseline: 1.4311x; 1.4311x over previous
//
#include <hip/hip_runtime.h>
#include <hip/hip_bf16.h>
#include <stdint.h>

typedef short short8 __attribute__((ext_vector_type(8)));
typedef float f32x4 __attribute__((ext_vector_type(4)));

// Problem constants
constexpr int SEQ   = 2048;   // T
constexpr int DM    = 1024;   // model dim
constexpr int NHEAD = 16;
constexpr int HD    = 64;     // head dim
constexpr int LDQ   = 1152;   // QKV row stride: 1024 Q | 64 K | 64 V
constexpr int BATCH = 2;

__device__ __forceinline__ unsigned short f2bf(float f) {
    union { float f; uint32_t u; } v; v.f = f;
    uint32_t u = v.u;
    uint32_t r = (u + 0x7fffu + ((u >> 16) & 1u)) >> 16;
    return (unsigned short)r;
}

// async global->LDS, 16B per lane. LDS dest = wave-uniform base + lane*16.
typedef __attribute__((address_space(1))) const void gvoid_t;
typedef __attribute__((address_space(3))) void lvoid_t;
__device__ __forceinline__ void gload16(const void* g, void* l) {
    __builtin_amdgcn_global_load_lds((gvoid_t*)g, (lvoid_t*)l, 16, 0, 0);
}

// ---------------- cast x (fp32 -> bf16), vectorized ----------------
__global__ __launch_bounds__(256) void cast_x_kernel(
        const float* __restrict__ x, unsigned short* __restrict__ xb, int n) {
    int i = (blockIdx.x * 256 + threadIdx.x) * 4;
    if (i >= n) return;
    const float4 v = *(const float4*)(x + i);
    ushort4 o;
    o.x = f2bf(v.x); o.y = f2bf(v.y); o.z = f2bf(v.z); o.w = f2bf(v.w);
    *(ushort4*)(xb + i) = o;
}

// ---- fused weight prep: cast+transpose Wq,Wk,Wv,Wo in one launch ----
__global__ __launch_bounds__(256) void prep_w_kernel(
        const float* __restrict__ Wq, const float* __restrict__ Wk,
        const float* __restrict__ Wv, const float* __restrict__ Wo,
        unsigned short* __restrict__ wtq, unsigned short* __restrict__ wot) {
    __shared__ unsigned short tile[32][33];
    int z = blockIdx.z;
    const float* W; unsigned short* Wt; int C;
    if (z == 0)      { W = Wq; Wt = wtq;                              C = DM; }
    else if (z == 1) { W = Wk; Wt = wtq + (size_t)DM * DM;            C = HD; }
    else if (z == 2) { W = Wv; Wt = wtq + (size_t)(DM + HD) * DM;     C = HD; }
    else             { W = Wo; Wt = wot;                              C = DM; }
    int c0 = blockIdx.x * 32, r0 = blockIdx.y * 32;
    if (c0 >= C) return;
    int tx = threadIdx.x & 31, ty = threadIdx.x >> 5;  // ty 0..7
    for (int i = ty; i < 32; i += 8)
        tile[i][tx] = f2bf(W[(size_t)(r0 + i) * C + (c0 + tx)]);
    __syncthreads();
    for (int i = ty; i < 32; i += 8)
        Wt[(size_t)(c0 + i) * DM + (r0 + tx)] = tile[tx][i];
}

// ------- transpose V slice of QKV (bf16 [seq][hd] -> Vt [hd][seq]) -------
__global__ __launch_bounds__(256) void transpose_v_kernel(
        const unsigned short* __restrict__ QKV, unsigned short* __restrict__ Vt) {
    __shared__ unsigned short tile[32][33];
    int b = blockIdx.z;
    int s0 = blockIdx.x * 32;   // seq
    int d0 = blockIdx.y * 32;   // head-dim
    int tx = threadIdx.x & 31, ty = threadIdx.x >> 5;
    const unsigned short* src = QKV + (size_t)b * SEQ * LDQ + DM + HD;
    for (int i = ty; i < 32; i += 8)
        tile[i][tx] = src[(size_t)(s0 + i) * LDQ + d0 + tx];
    __syncthreads();
    unsigned short* dst = Vt + (size_t)b * HD * SEQ;
    for (int i = ty; i < 32; i += 8)
        dst[(size_t)(d0 + i) * SEQ + s0 + tx] = tile[tx][i];
}

// ------------- GEMM: C[M,N] = A[M,K](bf16) @ Bt[N,K]^T(bf16) -------------
// 128x64 tile, BK=64 as two unpadded 128x32 half-tiles (gload16-compatible),
// 6 gload16 + 16 MFMA per wave per barrier-pair.
__global__ __launch_bounds__(256) void gemm_bt_kernel(
        const unsigned short* __restrict__ A,
        const unsigned short* __restrict__ Bt,
        void* __restrict__ Cout,
        int M, int N, int K, int out_bf16) {
    __shared__ unsigned short ldsA[2][128 * 32];
    __shared__ unsigned short ldsB[2][64 * 32];
    int lane = threadIdx.x & 63, wave = threadIdx.x >> 6;
    int ln = lane & 15, quad = lane >> 4;
    int wm = wave >> 1, wn = wave & 1;
    int m0 = blockIdx.y * 128, n0 = blockIdx.x * 64;

    int srow = lane >> 2, scol = (lane & 3) * 8;
    const unsigned short* gA0 = A + (size_t)(m0 + wave * 32 + srow) * K + scol;
    const unsigned short* gA1 = gA0 + (size_t)16 * K;
    const unsigned short* gB0 = Bt + (size_t)(n0 + wave * 16 + srow) * K + scol;

    f32x4 acc[4][2];
    for (int i = 0; i < 4; ++i)
        for (int jj = 0; jj < 2; ++jj) acc[i][jj] = f32x4{0, 0, 0, 0};

    for (int k0 = 0; k0 < K; k0 += 64) {
#pragma unroll
        for (int hh = 0; hh < 2; ++hh) {
            gload16(gA0 + k0 + hh * 32, &ldsA[hh][wave * 1024]);
            gload16(gA1 + k0 + hh * 32, &ldsA[hh][wave * 1024 + 512]);
            gload16(gB0 + k0 + hh * 32, &ldsB[hh][wave * 512]);
        }
        __syncthreads();
        short8 aF[2][4], bF[2][2];
#pragma unroll
        for (int hh = 0; hh < 2; ++hh) {
#pragma unroll
            for (int i = 0; i < 4; ++i)
                aF[hh][i] = *(const short8*)&ldsA[hh][(wm * 64 + i * 16 + ln) * 32 + quad * 8];
#pragma unroll
            for (int jj = 0; jj < 2; ++jj)
                bF[hh][jj] = *(const short8*)&ldsB[hh][(wn * 32 + jj * 16 + ln) * 32 + quad * 8];
        }
#pragma unroll
        for (int hh = 0; hh < 2; ++hh)
#pragma unroll
            for (int mt = 0; mt < 4; ++mt)
#pragma unroll
                for (int nt = 0; nt < 2; ++nt)
                    acc[mt][nt] = __builtin_amdgcn_mfma_f32_16x16x32_bf16(
                        aF[hh][mt], bF[hh][nt], acc[mt][nt], 0, 0, 0);
        __syncthreads();
    }

    if (out_bf16) {
        unsigned short* C = (unsigned short*)Cout;
#pragma unroll
        for (int mt = 0; mt < 4; ++mt)
            for (int nt = 0; nt < 2; ++nt)
                for (int r = 0; r < 4; ++r) {
                    int row = m0 + wm * 64 + mt * 16 + quad * 4 + r;
                    int col = n0 + wn * 32 + nt * 16 + ln;
                    C[(size_t)row * N + col] = f2bf(acc[mt][nt][r]);
                }
    } else {
        float* C = (float*)Cout;
#pragma unroll
        for (int mt = 0; mt < 4; ++mt)
            for (int nt = 0; nt < 2; ++nt)
                for (int r = 0; r < 4; ++r) {
                    int row = m0 + wm * 64 + mt * 16 + quad * 4 + r;
                    int col = n0 + wn * 32 + nt * 16 + ln;
                    C[(size_t)row * N + col] = acc[mt][nt][r];
                }
    }
}

// ---------------- flash attention (multi-query, causal) ----------------
// Block = 4 waves, wave w -> q-tile j = jg*4 + w (16 queries). Per 32-key
// step, K(32x64) and Vt(64x32) are staged ONCE per block into double-buffered
// LDS via global_load_lds (async prefetch issued right after the barrier,
// hidden under compute). Xor-swizzled LDS layouts (no padding allowed with
// global_load_lds) make the B-fragment ds_read_b128 patterns conflict-free.
// Blocks ordered heavy-first (descending jg) for tail shaping.
// Constant-max streaming softmax (scores bounded; exp can't overflow).
__global__ __launch_bounds__(256) void attn_kernel(
        const unsigned short* __restrict__ QKV,
        const unsigned short* __restrict__ Vt,
        unsigned short* __restrict__ Y) {
    __shared__ unsigned short ldsK[2][32 * 64];   // [buf][r*64 + cb'*8 + e], cb' = cb ^ (r&7)
    __shared__ unsigned short ldsV[2][64 * 32];   // [buf][r*32 + cb'*8 + e], cb' = cb ^ ((r>>1)&3)
    __shared__ unsigned short pbuf[4][16][40];    // per-wave P round-trip

    int lane = threadIdx.x & 63, wave = threadIdx.x >> 6;
    int ln = lane & 15, quad = lane >> 4;
    int bid = blockIdx.x;
    int jg = 31 - (bid >> 5);             // heavy-first: large key ranges dispatch first
    int bh = bid & 31;
    int h = bh & 15, b = bh >> 4;
    int q0 = (jg * 4 + wave) * 16;        // this wave's 16 queries
    const size_t baseRow = (size_t)b * SEQ;
    const unsigned short* Vb = Vt + (size_t)b * HD * SEQ;

    // staging addresses (per-thread global source; LDS dest is wave-uniform)
    int tK_r = threadIdx.x >> 3;                       // 0..31
    int tK_cb = (threadIdx.x & 7) ^ (tK_r & 7);        // xor swizzle
    const unsigned short* gK = QKV + (baseRow + tK_r) * LDQ + DM + tK_cb * 8;
    int tV_r = threadIdx.x >> 2;                       // 0..63
    int tV_cb = (threadIdx.x & 3) ^ ((tV_r >> 1) & 3);
    const unsigned short* gV = Vb + (size_t)tV_r * SEQ + tV_cb * 8;

    // Q fragments (A-layout)
    short8 aQ0, aQ1;
    {
        const unsigned short* qp = QKV + (baseRow + q0 + ln) * LDQ + h * HD + quad * 8;
        aQ0 = *(const short8*)(qp);
        aQ1 = *(const short8*)(qp + 32);
    }

    float lsum[4] = {0.f, 0.f, 0.f, 0.f};
    f32x4 o[4];
    for (int nt = 0; nt < 4; ++nt) o[nt] = f32x4{0, 0, 0, 0};

    const float c_exp = 0.1803368802f;    // 0.125 * log2(e)
    const int nsteps = 2 * jg + 2;        // covers keys up to (jg*4+3)*16+15
    const int mysmax = q0 + 15;

    // prologue: stage step 0 into buf 0
    gload16(gK, &ldsK[0][wave * 512]);
    gload16(gV, &ldsV[0][wave * 512]);

    for (int it = 0; it < nsteps; ++it) {
        int s0 = it * 32;
        __syncthreads();                   // staging of buf(it&1) complete
        if (it + 1 < nsteps) {             // async prefetch next step
            int sn = s0 + 32;
            gload16(gK + (size_t)sn * LDQ, &ldsK[(it + 1) & 1][wave * 512]);
            gload16(gV + sn,               &ldsV[(it + 1) & 1][wave * 512]);
        }
        if (s0 <= mysmax) {                // wave-uniform
            const unsigned short* Kb = ldsK[it & 1];
            const unsigned short* Vbuf = ldsV[it & 1];
            // K fragments (B-layout): key n = c*16+ln, k = quad*8 + 32*hh
            short8 bK[2][2];
#pragma unroll
            for (int c = 0; c < 2; ++c) {
                int r = c * 16 + ln;
                bK[c][0] = *(const short8*)&Kb[r * 64 + ((quad ^ (ln & 7)) * 8)];
                bK[c][1] = *(const short8*)&Kb[r * 64 + (((quad + 4) ^ (ln & 7)) * 8)];
            }
            // V fragments (B-layout): n = hd = nt*16+ln, k = key = quad*8+j
            short8 bV[4];
#pragma unroll
            for (int nt = 0; nt < 4; ++nt) {
                int row = nt * 16 + ln;
                bV[nt] = *(const short8*)&Vbuf[row * 32 + ((quad ^ ((ln >> 1) & 3)) * 8)];
            }

            float p[2][4];
#pragma unroll
            for (int c = 0; c < 2; ++c) {
                f32x4 s = {0, 0, 0, 0};
                s = __builtin_amdgcn_mfma_f32_16x16x32_bf16(aQ0, bK[c][0], s, 0, 0, 0);
                s = __builtin_amdgcn_mfma_f32_16x16x32_bf16(aQ1, bK[c][1], s, 0, 0, 0);
                int srow = s0 + c * 16 + ln;
                for (int r = 0; r < 4; ++r) {
                    int ti = q0 + quad * 4 + r;
                    float e = __builtin_exp2f(s[r] * c_exp);
                    p[c][r] = (srow > ti) ? 0.f : e;   // causal mask
                }
            }
#pragma unroll
            for (int r = 0; r < 4; ++r) lsum[r] += p[0][r] + p[1][r];

            // P: C-layout -> LDS -> A-layout (per-wave private, no barrier)
#pragma unroll
            for (int c = 0; c < 2; ++c)
                for (int r = 0; r < 4; ++r)
                    pbuf[wave][quad * 4 + r][c * 16 + ln] = f2bf(p[c][r]);
            short8 aP = *(const short8*)&pbuf[wave][ln][quad * 8];
#pragma unroll
            for (int nt = 0; nt < 4; ++nt)
                o[nt] = __builtin_amdgcn_mfma_f32_16x16x32_bf16(aP, bV[nt], o[nt], 0, 0, 0);
        }
    }

    // epilogue: reduce l across the 16 lanes of each quad, then Y = O / l
    for (int off = 1; off < 16; off <<= 1)
#pragma unroll
        for (int r = 0; r < 4; ++r) lsum[r] += __shfl_xor(lsum[r], off);
#pragma unroll
    for (int r = 0; r < 4; ++r) {
        float inv = 1.0f / lsum[r];
        int t_idx = q0 + quad * 4 + r;
        unsigned short* yp = Y + (baseRow + t_idx) * DM + h * HD + ln;
        for (int nt = 0; nt < 4; ++nt)
            yp[nt * 16] = f2bf(o[nt][r] * inv);
    }
}

extern "C" void kernel_launch(void* const* d_in, const int* in_sizes, int n_in,
                              void* d_out, int out_size, void* d_ws, size_t ws_size,
                              hipStream_t stream) {
    const float* x  = (const float*)d_in[0];
    const float* Wq = (const float*)d_in[1];
    const float* Wk = (const float*)d_in[2];
    const float* Wv = (const float*)d_in[3];
    const float* Wo = (const float*)d_in[4];
    float* out = (float*)d_out;

    char* ws = (char*)d_ws;
    // workspace layout; Vt aliases xb (xb is dead after the QKV GEMM)
    unsigned short* xb  = (unsigned short*)(ws);                // 4096x1024 bf16  (8 MB)
    unsigned short* Vt  = (unsigned short*)(ws);                // 2x64x2048 bf16  (alias)
    unsigned short* wtq = (unsigned short*)(ws + 8388608);      // 1152x1024 bf16: Wq^T|Wk^T|Wv^T
    unsigned short* wot = (unsigned short*)(ws + 10747904);     // 1024x1024 bf16  (Wo^T)
    unsigned short* qkv = (unsigned short*)(ws + 12845056);     // 4096x1152 bf16
    unsigned short* y   = (unsigned short*)(ws + 22282240);     // 4096x1024 bf16

    const int BT = BATCH * SEQ;  // 4096 rows

    hipLaunchKernelGGL(cast_x_kernel, dim3(BT * DM / 4 / 256), dim3(256), 0, stream,
                       x, xb, BT * DM);
    hipLaunchKernelGGL(prep_w_kernel, dim3(DM / 32, DM / 32, 4), dim3(256), 0, stream,
                       Wq, Wk, Wv, Wo, wtq, wot);

    // QKV = x @ [Wq|Wk|Wv]  -> bf16   (576 blocks)
    hipLaunchKernelGGL(gemm_bt_kernel, dim3(LDQ / 64, BT / 128), dim3(256), 0, stream,
                       xb, wtq, (void*)qkv, BT, LDQ, DM, 1);

    // V -> Vt [b][hd][seq]   (xb dead from here; Vt aliases it)
    hipLaunchKernelGGL(transpose_v_kernel, dim3(SEQ / 32, HD / 32, BATCH), dim3(256), 0, stream,
                       qkv, Vt);

    // flash attention (block-staged K/V, dbuf) -> Y bf16   (1024 blocks)
    hipLaunchKernelGGL(attn_kernel, dim3(32 * 32), dim3(256), 0, stream,
                       qkv, Vt, y);

    // out = Y @ Wo -> fp32   (512 blocks)
    hipLaunchKernelGGL(gemm_bt_kernel, dim3(DM / 64, BT / 128), dim3(256), 0, stream,
                       y, wot, (void*)out, BT, DM, DM, 0);
}

// Round 6
// 173.466 us; speedup vs baseline: 1.5475x; 1.0813x over previous
//
#include <hip/hip_runtime.h>
#include <hip/hip_bf16.h>
#include <stdint.h>

typedef short short8 __attribute__((ext_vector_type(8)));
typedef float f32x4 __attribute__((ext_vector_type(4)));

// Problem constants
constexpr int SEQ   = 2048;   // T
constexpr int DM    = 1024;   // model dim
constexpr int NHEAD = 16;
constexpr int HD    = 64;     // head dim
constexpr int LDQ   = 1152;   // QKV row stride: 1024 Q | 64 K | 64 V
constexpr int BATCH = 2;

__device__ __forceinline__ unsigned short f2bf(float f) {
    union { float f; uint32_t u; } v; v.f = f;
    uint32_t u = v.u;
    uint32_t r = (u + 0x7fffu + ((u >> 16) & 1u)) >> 16;
    return (unsigned short)r;
}

// async global->LDS, 16B per lane. LDS dest = wave-uniform base + lane*16.
typedef __attribute__((address_space(1))) const void gvoid_t;
typedef __attribute__((address_space(3))) void lvoid_t;
__device__ __forceinline__ void gload16(const void* g, void* l) {
    __builtin_amdgcn_global_load_lds((gvoid_t*)g, (lvoid_t*)l, 16, 0, 0);
}

// ---------------- cast x (fp32 -> bf16), vectorized ----------------
__global__ __launch_bounds__(256) void cast_x_kernel(
        const float* __restrict__ x, unsigned short* __restrict__ xb, int n) {
    int i = (blockIdx.x * 256 + threadIdx.x) * 4;
    if (i >= n) return;
    const float4 v = *(const float4*)(x + i);
    ushort4 o;
    o.x = f2bf(v.x); o.y = f2bf(v.y); o.z = f2bf(v.z); o.w = f2bf(v.w);
    *(ushort4*)(xb + i) = o;
}

// ---- fused weight prep: cast+transpose Wq,Wk,Wv,Wo in one launch ----
__global__ __launch_bounds__(256) void prep_w_kernel(
        const float* __restrict__ Wq, const float* __restrict__ Wk,
        const float* __restrict__ Wv, const float* __restrict__ Wo,
        unsigned short* __restrict__ wtq, unsigned short* __restrict__ wot) {
    __shared__ unsigned short tile[32][33];
    int z = blockIdx.z;
    const float* W; unsigned short* Wt; int C;
    if (z == 0)      { W = Wq; Wt = wtq;                              C = DM; }
    else if (z == 1) { W = Wk; Wt = wtq + (size_t)DM * DM;            C = HD; }
    else if (z == 2) { W = Wv; Wt = wtq + (size_t)(DM + HD) * DM;     C = HD; }
    else             { W = Wo; Wt = wot;                              C = DM; }
    int c0 = blockIdx.x * 32, r0 = blockIdx.y * 32;
    if (c0 >= C) return;
    int tx = threadIdx.x & 31, ty = threadIdx.x >> 5;  // ty 0..7
    for (int i = ty; i < 32; i += 8)
        tile[i][tx] = f2bf(W[(size_t)(r0 + i) * C + (c0 + tx)]);
    __syncthreads();
    for (int i = ty; i < 32; i += 8)
        Wt[(size_t)(c0 + i) * DM + (r0 + tx)] = tile[tx][i];
}

// ------------- GEMM: C[M,N] = A[M,K](bf16) @ Bt[N,K]^T(bf16) -------------
// 128x64 tile, BK=64 (two unpadded 128x32 half-tiles), DOUBLE-BUFFERED
// global_load_lds staging: prefetch for step it+1 issued right after the
// barrier of step it, so the 6 in-flight gloads/wave hide under 16 MFMA +
// 12 ds_read_b128. One barrier per K-step. LDS 48 KB -> 3 blocks/CU.
// If VtOut != null, the V column block (n0==1088) also writes V transposed
// ([b][hd][seq]) so no separate transpose kernel is needed.
__global__ __launch_bounds__(256) void gemm_bt_kernel(
        const unsigned short* __restrict__ A,
        const unsigned short* __restrict__ Bt,
        void* __restrict__ Cout,
        unsigned short* __restrict__ VtOut,
        int M, int N, int K, int out_bf16) {
    __shared__ unsigned short ldsA[2][2][128 * 32];
    __shared__ unsigned short ldsB[2][2][64 * 32];
    int lane = threadIdx.x & 63, wave = threadIdx.x >> 6;
    int ln = lane & 15, quad = lane >> 4;
    int wm = wave >> 1, wn = wave & 1;
    int m0 = blockIdx.y * 128, n0 = blockIdx.x * 64;

    int srow = lane >> 2, scol = (lane & 3) * 8;
    const unsigned short* gA0 = A + (size_t)(m0 + wave * 32 + srow) * K + scol;
    const unsigned short* gA1 = gA0 + (size_t)16 * K;
    const unsigned short* gB0 = Bt + (size_t)(n0 + wave * 16 + srow) * K + scol;

    f32x4 acc[4][2];
    for (int i = 0; i < 4; ++i)
        for (int jj = 0; jj < 2; ++jj) acc[i][jj] = f32x4{0, 0, 0, 0};

    auto stage = [&](int k0, int buf) {
#pragma unroll
        for (int hh = 0; hh < 2; ++hh) {
            gload16(gA0 + k0 + hh * 32, &ldsA[buf][hh][wave * 1024]);
            gload16(gA1 + k0 + hh * 32, &ldsA[buf][hh][wave * 1024 + 512]);
            gload16(gB0 + k0 + hh * 32, &ldsB[buf][hh][wave * 512]);
        }
    };

    stage(0, 0);
    int niter = K >> 6;
    for (int it = 0; it < niter; ++it) {
        __syncthreads();                       // buf (it&1) ready, prev compute done
        if (it + 1 < niter) stage((it + 1) << 6, (it + 1) & 1);
        int buf = it & 1;
        short8 aF[2][4], bF[2][2];
#pragma unroll
        for (int hh = 0; hh < 2; ++hh) {
#pragma unroll
            for (int i = 0; i < 4; ++i)
                aF[hh][i] = *(const short8*)&ldsA[buf][hh][(wm * 64 + i * 16 + ln) * 32 + quad * 8];
#pragma unroll
            for (int jj = 0; jj < 2; ++jj)
                bF[hh][jj] = *(const short8*)&ldsB[buf][hh][(wn * 32 + jj * 16 + ln) * 32 + quad * 8];
        }
#pragma unroll
        for (int hh = 0; hh < 2; ++hh)
#pragma unroll
            for (int mt = 0; mt < 4; ++mt)
#pragma unroll
                for (int nt = 0; nt < 2; ++nt)
                    acc[mt][nt] = __builtin_amdgcn_mfma_f32_16x16x32_bf16(
                        aF[hh][mt], bF[hh][nt], acc[mt][nt], 0, 0, 0);
    }

    if (out_bf16) {
        unsigned short* C = (unsigned short*)Cout;
#pragma unroll
        for (int mt = 0; mt < 4; ++mt)
            for (int nt = 0; nt < 2; ++nt)
                for (int r = 0; r < 4; ++r) {
                    int row = m0 + wm * 64 + mt * 16 + quad * 4 + r;
                    int col = n0 + wn * 32 + nt * 16 + ln;
                    C[(size_t)row * N + col] = f2bf(acc[mt][nt][r]);
                }
        if (VtOut != nullptr && n0 == DM + HD) {   // V block: also write transposed
#pragma unroll
            for (int mt = 0; mt < 4; ++mt)
                for (int nt = 0; nt < 2; ++nt)
                    for (int r = 0; r < 4; ++r) {
                        int row = m0 + wm * 64 + mt * 16 + quad * 4 + r;
                        int d = wn * 32 + nt * 16 + ln;          // 0..63
                        int bb = row >> 11, s = row & 2047;
                        VtOut[((size_t)bb * HD + d) * SEQ + s] = f2bf(acc[mt][nt][r]);
                    }
        }
    } else {
        float* C = (float*)Cout;
#pragma unroll
        for (int mt = 0; mt < 4; ++mt)
            for (int nt = 0; nt < 2; ++nt)
                for (int r = 0; r < 4; ++r) {
                    int row = m0 + wm * 64 + mt * 16 + quad * 4 + r;
                    int col = n0 + wn * 32 + nt * 16 + ln;
                    C[(size_t)row * N + col] = acc[mt][nt][r];
                }
    }
}

// ---------------- flash attention (multi-query, causal) ----------------
// 64-key steps: block stages K(64x64) + Vt(64x64) into double-buffered LDS
// via global_load_lds (swizzle on the GLOBAL chunk index; LDS dest stays
// wave-uniform base + lane*16). 4 waves share the tiles; wave w owns q-tile
// jg*4+w. Every wave has exactly jg full (mask-free) steps + 1 partial step.
// Constant-max streaming softmax; P stored to pbuf by truncation (>>16).
__global__ __launch_bounds__(256) void attn_kernel(
        const unsigned short* __restrict__ QKV,
        const unsigned short* __restrict__ Vt,
        unsigned short* __restrict__ Y) {
    __shared__ unsigned short ldsK[2][64 * 64];   // [key][hd-chunk swizzled]
    __shared__ unsigned short ldsV[2][64 * 64];   // [hd][key-chunk swizzled]
    __shared__ unsigned short pbuf[4][16][72];    // per-wave P (16q x 64k, +8 pad)

    int lane = threadIdx.x & 63, wave = threadIdx.x >> 6;
    int ln = lane & 15, quad = lane >> 4;
    int bid = blockIdx.x;
    int jg = 31 - (bid >> 5);             // heavy-first
    int bh = bid & 31;
    int h = bh & 15, b = bh >> 4;
    int q0 = (jg * 4 + wave) * 16;
    const size_t baseRow = (size_t)b * SEQ;
    const unsigned short* Vb = Vt + (size_t)b * HD * SEQ;

    // staging mapping: thread t covers row trow(+32*rr), LDS chunk tcb;
    // global chunk = tcb ^ (trow&7)  (row&7 invariant under +32 and +64*s0)
    int t = threadIdx.x;
    int trow = t >> 3, tcb = t & 7;
    int cbg = tcb ^ (trow & 7);
    const unsigned short* gK = QKV + (baseRow + trow) * LDQ + DM + cbg * 8;
    const unsigned short* gV = Vb + (size_t)trow * SEQ + cbg * 8;
    int dstoff = trow * 64 + tcb * 8;

    auto stageKV = [&](int s0n, int buf) {
#pragma unroll
        for (int rr = 0; rr < 2; ++rr) {
            gload16(gK + (size_t)(s0n + 32 * rr) * LDQ, &ldsK[buf][dstoff + rr * 2048]);
            gload16(gV + (size_t)32 * rr * SEQ + s0n,   &ldsV[buf][dstoff + rr * 2048]);
        }
    };

    // Q fragments (A-layout)
    short8 aQ0, aQ1;
    {
        const unsigned short* qp = QKV + (baseRow + q0 + ln) * LDQ + h * HD + quad * 8;
        aQ0 = *(const short8*)(qp);
        aQ1 = *(const short8*)(qp + 32);
    }

    float lsum[4] = {0.f, 0.f, 0.f, 0.f};
    f32x4 o[4];
    for (int nt = 0; nt < 4; ++nt) o[nt] = f32x4{0, 0, 0, 0};

    const float c_exp = 0.1803368802f;    // 0.125 * log2(e)

    auto computeStep = [&](int s0, int buf, bool partial) {
        const unsigned short* Kb = ldsK[buf];
        const unsigned short* Vf = ldsV[buf];
#pragma unroll
        for (int c = 0; c < 4; ++c) {
            int kbase = s0 + c * 16;
            if (partial && kbase > q0 + 15) {   // fully masked tile: zero P
#pragma unroll
                for (int r = 0; r < 4; ++r)
                    pbuf[wave][quad * 4 + r][c * 16 + ln] = 0;
                continue;
            }
            short8 k0f = *(const short8*)&Kb[(c * 16 + ln) * 64 + ((quad ^ (ln & 7)) * 8)];
            short8 k1f = *(const short8*)&Kb[(c * 16 + ln) * 64 + (((4 + quad) ^ (ln & 7)) * 8)];
            f32x4 s = {0, 0, 0, 0};
            s = __builtin_amdgcn_mfma_f32_16x16x32_bf16(aQ0, k0f, s, 0, 0, 0);
            s = __builtin_amdgcn_mfma_f32_16x16x32_bf16(aQ1, k1f, s, 0, 0, 0);
            bool diag = partial && (kbase + 15 > q0);
#pragma unroll
            for (int r = 0; r < 4; ++r) {
                float e = __builtin_exp2f(s[r] * c_exp);
                if (diag && (kbase + ln > q0 + quad * 4 + r)) e = 0.f;  // causal
                lsum[r] += e;
                pbuf[wave][quad * 4 + r][c * 16 + ln] =
                    (unsigned short)(__float_as_uint(e) >> 16);        // bf16 trunc
            }
        }
        short8 aP0 = *(const short8*)&pbuf[wave][ln][quad * 8];
        short8 aP1 = *(const short8*)&pbuf[wave][ln][32 + quad * 8];
#pragma unroll
        for (int nt = 0; nt < 4; ++nt) {
            short8 v0 = *(const short8*)&Vf[(nt * 16 + ln) * 64 + ((quad ^ (ln & 7)) * 8)];
            short8 v1 = *(const short8*)&Vf[(nt * 16 + ln) * 64 + (((4 + quad) ^ (ln & 7)) * 8)];
            o[nt] = __builtin_amdgcn_mfma_f32_16x16x32_bf16(aP0, v0, o[nt], 0, 0, 0);
            o[nt] = __builtin_amdgcn_mfma_f32_16x16x32_bf16(aP1, v1, o[nt], 0, 0, 0);
        }
    };

    stageKV(0, 0);
    for (int it = 0; it < jg; ++it) {          // full steps, mask-free
        __syncthreads();
        stageKV((it + 1) * 64, (it + 1) & 1);
        computeStep(it * 64, it & 1, false);
    }
    __syncthreads();
    computeStep(jg * 64, jg & 1, true);        // the one partial step

    // epilogue: reduce l across the 16 lanes of each quad, then Y = O / l
    for (int off = 1; off < 16; off <<= 1)
#pragma unroll
        for (int r = 0; r < 4; ++r) lsum[r] += __shfl_xor(lsum[r], off);
#pragma unroll
    for (int r = 0; r < 4; ++r) {
        float inv = 1.0f / lsum[r];
        int t_idx = q0 + quad * 4 + r;
        unsigned short* yp = Y + (baseRow + t_idx) * DM + h * HD + ln;
        for (int nt = 0; nt < 4; ++nt)
            yp[nt * 16] = f2bf(o[nt][r] * inv);
    }
}

extern "C" void kernel_launch(void* const* d_in, const int* in_sizes, int n_in,
                              void* d_out, int out_size, void* d_ws, size_t ws_size,
                              hipStream_t stream) {
    const float* x  = (const float*)d_in[0];
    const float* Wq = (const float*)d_in[1];
    const float* Wk = (const float*)d_in[2];
    const float* Wv = (const float*)d_in[3];
    const float* Wo = (const float*)d_in[4];
    float* out = (float*)d_out;

    char* ws = (char*)d_ws;
    // workspace (21.8 MB): slot0 is xb until qkv-gemm completes, then y.
    unsigned short* xb  = (unsigned short*)(ws);                // 4096x1024 bf16 (8 MB)
    unsigned short* y   = (unsigned short*)(ws);                // alias: attn out
    unsigned short* wtq = (unsigned short*)(ws + 8388608);      // 1152x1024 bf16
    unsigned short* wot = (unsigned short*)(ws + 10747904);     // 1024x1024 bf16
    unsigned short* qkv = (unsigned short*)(ws + 12845056);     // 4096x1152 bf16
    unsigned short* Vt  = (unsigned short*)(ws + 22282240);     // 2x64x2048 bf16 (0.5 MB)

    const int BT = BATCH * SEQ;  // 4096 rows

    hipLaunchKernelGGL(cast_x_kernel, dim3(BT * DM / 4 / 256), dim3(256), 0, stream,
                       x, xb, BT * DM);
    hipLaunchKernelGGL(prep_w_kernel, dim3(DM / 32, DM / 32, 4), dim3(256), 0, stream,
                       Wq, Wk, Wv, Wo, wtq, wot);

    // QKV = x @ [Wq|Wk|Wv] -> bf16; V block also written transposed to Vt
    hipLaunchKernelGGL(gemm_bt_kernel, dim3(LDQ / 64, BT / 128), dim3(256), 0, stream,
                       xb, wtq, (void*)qkv, Vt, BT, LDQ, DM, 1);

    // flash attention (64-key dbuf steps) -> y bf16 (overwrites xb, now dead)
    hipLaunchKernelGGL(attn_kernel, dim3(32 * 32), dim3(256), 0, stream,
                       qkv, Vt, y);

    // out = y @ Wo -> fp32
    hipLaunchKernelGGL(gemm_bt_kernel, dim3(DM / 64, BT / 128), dim3(256), 0, stream,
                       y, wot, (void*)out, nullptr, BT, DM, DM, 0);
}

// Round 7
// 168.388 us; speedup vs baseline: 1.5941x; 1.0302x over previous
//
#include <hip/hip_runtime.h>
#include <hip/hip_bf16.h>
#include <stdint.h>

typedef short short8 __attribute__((ext_vector_type(8)));
typedef float f32x4 __attribute__((ext_vector_type(4)));

// Problem constants
constexpr int SEQ   = 2048;   // T
constexpr int DM    = 1024;   // model dim
constexpr int NHEAD = 16;
constexpr int HD    = 64;     // head dim
constexpr int LDQ   = 1152;   // QKV row stride: 1024 Q | 64 K | 64 V
constexpr int BATCH = 2;

__device__ __forceinline__ unsigned short f2bf(float f) {
    union { float f; uint32_t u; } v; v.f = f;
    uint32_t u = v.u;
    uint32_t r = (u + 0x7fffu + ((u >> 16) & 1u)) >> 16;
    return (unsigned short)r;
}

// async global->LDS, 16B per lane. LDS dest = wave-uniform base + lane*16.
typedef __attribute__((address_space(1))) const void gvoid_t;
typedef __attribute__((address_space(3))) void lvoid_t;
__device__ __forceinline__ void gload16(const void* g, void* l) {
    __builtin_amdgcn_global_load_lds((gvoid_t*)g, (lvoid_t*)l, 16, 0, 0);
}

// ---------------- cast x (fp32 -> bf16), vectorized ----------------
__global__ __launch_bounds__(256) void cast_x_kernel(
        const float* __restrict__ x, unsigned short* __restrict__ xb, int n) {
    int i = (blockIdx.x * 256 + threadIdx.x) * 4;
    if (i >= n) return;
    const float4 v = *(const float4*)(x + i);
    ushort4 o;
    o.x = f2bf(v.x); o.y = f2bf(v.y); o.z = f2bf(v.z); o.w = f2bf(v.w);
    *(ushort4*)(xb + i) = o;
}

// ---- fused weight prep: cast+transpose Wq,Wk,Wv,Wo in one launch ----
__global__ __launch_bounds__(256) void prep_w_kernel(
        const float* __restrict__ Wq, const float* __restrict__ Wk,
        const float* __restrict__ Wv, const float* __restrict__ Wo,
        unsigned short* __restrict__ wtq, unsigned short* __restrict__ wot) {
    __shared__ unsigned short tile[32][33];
    int z = blockIdx.z;
    const float* W; unsigned short* Wt; int C;
    if (z == 0)      { W = Wq; Wt = wtq;                              C = DM; }
    else if (z == 1) { W = Wk; Wt = wtq + (size_t)DM * DM;            C = HD; }
    else if (z == 2) { W = Wv; Wt = wtq + (size_t)(DM + HD) * DM;     C = HD; }
    else             { W = Wo; Wt = wot;                              C = DM; }
    int c0 = blockIdx.x * 32, r0 = blockIdx.y * 32;
    if (c0 >= C) return;
    int tx = threadIdx.x & 31, ty = threadIdx.x >> 5;  // ty 0..7
    for (int i = ty; i < 32; i += 8)
        tile[i][tx] = f2bf(W[(size_t)(r0 + i) * C + (c0 + tx)]);
    __syncthreads();
    for (int i = ty; i < 32; i += 8)
        Wt[(size_t)(c0 + i) * DM + (r0 + tx)] = tile[tx][i];
}

// ------------- GEMM: C[M,N] = A[M,K](bf16) @ Bt[N,K]^T(bf16) -------------
// 64x64 tile for GRID size (qkv: 1152 blocks = 4.5/CU; out: 1024 = 4/CU).
// BK=64 staged as one 64x64 LDS tile per operand via global_load_lds with
// (row&7) xor chunk swizzle -> all fragment ds_read_b128 are 2-way/bank
// (free). Double-buffered (32 KB LDS -> 5 blocks/CU resident). 4 waves in
// 2x2; each wave 32x32 out via 2x2x2hh of mfma_f32_16x16x32_bf16.
// If VtOut != null, the V column block (n0==1088) also writes V transposed.
__global__ __launch_bounds__(256) void gemm_bt_kernel(
        const unsigned short* __restrict__ A,
        const unsigned short* __restrict__ Bt,
        void* __restrict__ Cout,
        unsigned short* __restrict__ VtOut,
        int M, int N, int K, int out_bf16) {
    __shared__ unsigned short ldsA[2][64 * 64];
    __shared__ unsigned short ldsB[2][64 * 64];
    int lane = threadIdx.x & 63, wave = threadIdx.x >> 6;
    int ln = lane & 15, quad = lane >> 4;
    int wm = wave >> 1, wn = wave & 1;
    int m0 = blockIdx.y * 64, n0 = blockIdx.x * 64;

    // staging: thread t covers row trow (+32), LDS chunk tcb; global chunk
    // gcb = tcb ^ (trow&7)  ((row+32)&7 == row&7, so one gcb serves both rr)
    int t = threadIdx.x;
    int trow = t >> 3, tcb = t & 7;
    int gcb = tcb ^ (trow & 7);
    const unsigned short* gA = A + (size_t)(m0 + trow) * K + gcb * 8;
    const unsigned short* gA2 = gA + (size_t)32 * K;
    const unsigned short* gB = Bt + (size_t)(n0 + trow) * K + gcb * 8;
    const unsigned short* gB2 = gB + (size_t)32 * K;
    int dst = t * 8;   // shorts; rr=1 adds 2048

    auto stage = [&](int k0, int buf) {
        gload16(gA + k0, &ldsA[buf][dst]);
        gload16(gA2 + k0, &ldsA[buf][dst + 2048]);
        gload16(gB + k0, &ldsB[buf][dst]);
        gload16(gB2 + k0, &ldsB[buf][dst + 2048]);
    };

    f32x4 acc[2][2];
    for (int i = 0; i < 2; ++i)
        for (int jj = 0; jj < 2; ++jj) acc[i][jj] = f32x4{0, 0, 0, 0};

    stage(0, 0);
    int niter = K >> 6;
    for (int it = 0; it < niter; ++it) {
        __syncthreads();
        if (it + 1 < niter) stage((it + 1) << 6, (it + 1) & 1);
        const unsigned short* La = ldsA[it & 1];
        const unsigned short* Lb = ldsB[it & 1];
        short8 aF[2][2], bF[2][2];
#pragma unroll
        for (int hh = 0; hh < 2; ++hh) {
            int kc = hh * 4 + quad;
#pragma unroll
            for (int mt = 0; mt < 2; ++mt)
                aF[hh][mt] = *(const short8*)&La[(wm * 32 + mt * 16 + ln) * 64 +
                                                ((kc ^ (ln & 7)) * 8)];
#pragma unroll
            for (int nt = 0; nt < 2; ++nt)
                bF[hh][nt] = *(const short8*)&Lb[(wn * 32 + nt * 16 + ln) * 64 +
                                                ((kc ^ (ln & 7)) * 8)];
        }
#pragma unroll
        for (int hh = 0; hh < 2; ++hh)
#pragma unroll
            for (int mt = 0; mt < 2; ++mt)
#pragma unroll
                for (int nt = 0; nt < 2; ++nt)
                    acc[mt][nt] = __builtin_amdgcn_mfma_f32_16x16x32_bf16(
                        aF[hh][mt], bF[hh][nt], acc[mt][nt], 0, 0, 0);
    }

    if (out_bf16) {
        unsigned short* C = (unsigned short*)Cout;
#pragma unroll
        for (int mt = 0; mt < 2; ++mt)
            for (int nt = 0; nt < 2; ++nt)
                for (int r = 0; r < 4; ++r) {
                    int row = m0 + wm * 32 + mt * 16 + quad * 4 + r;
                    int col = n0 + wn * 32 + nt * 16 + ln;
                    C[(size_t)row * N + col] = f2bf(acc[mt][nt][r]);
                }
        if (VtOut != nullptr && n0 == DM + HD) {   // V block: also write transposed
#pragma unroll
            for (int mt = 0; mt < 2; ++mt)
                for (int nt = 0; nt < 2; ++nt)
                    for (int r = 0; r < 4; ++r) {
                        int row = m0 + wm * 32 + mt * 16 + quad * 4 + r;
                        int d = wn * 32 + nt * 16 + ln;          // 0..63
                        int bb = row >> 11, s = row & 2047;
                        VtOut[((size_t)bb * HD + d) * SEQ + s] = f2bf(acc[mt][nt][r]);
                    }
        }
    } else {
        float* C = (float*)Cout;
#pragma unroll
        for (int mt = 0; mt < 2; ++mt)
            for (int nt = 0; nt < 2; ++nt)
                for (int r = 0; r < 4; ++r) {
                    int row = m0 + wm * 32 + mt * 16 + quad * 4 + r;
                    int col = n0 + wn * 32 + nt * 16 + ln;
                    C[(size_t)row * N + col] = acc[mt][nt][r];
                }
    }
}

// ---------------- flash attention (multi-query, causal) ----------------
// 64-key steps: block stages K(64x64) + Vt(64x64) into double-buffered LDS
// via global_load_lds ((row&7) xor chunk swizzle). 4 waves share the tiles;
// wave w owns q-tile jg*4+w: jg mask-free steps + 1 partial step.
// pbuf uses the same xor swizzle (no pad) -> LDS total 40960 B = exactly
// 4 blocks/CU. Constant-max streaming softmax; P stored by truncation.
__global__ __launch_bounds__(256) void attn_kernel(
        const unsigned short* __restrict__ QKV,
        const unsigned short* __restrict__ Vt,
        unsigned short* __restrict__ Y) {
    __shared__ unsigned short ldsK[2][64 * 64];
    __shared__ unsigned short ldsV[2][64 * 64];
    __shared__ unsigned short pbuf[4][16 * 64];   // swizzled, per-wave

    int lane = threadIdx.x & 63, wave = threadIdx.x >> 6;
    int ln = lane & 15, quad = lane >> 4;
    int bid = blockIdx.x;
    int jg = 31 - (bid >> 5);             // heavy-first
    int bh = bid & 31;
    int h = bh & 15, b = bh >> 4;
    int q0 = (jg * 4 + wave) * 16;
    const size_t baseRow = (size_t)b * SEQ;
    const unsigned short* Vb = Vt + (size_t)b * HD * SEQ;

    int t = threadIdx.x;
    int trow = t >> 3, tcb = t & 7;
    int cbg = tcb ^ (trow & 7);
    const unsigned short* gK = QKV + (baseRow + trow) * LDQ + DM + cbg * 8;
    const unsigned short* gV = Vb + (size_t)trow * SEQ + cbg * 8;
    int dstoff = trow * 64 + tcb * 8;

    auto stageKV = [&](int s0n, int buf) {
#pragma unroll
        for (int rr = 0; rr < 2; ++rr) {
            gload16(gK + (size_t)(s0n + 32 * rr) * LDQ, &ldsK[buf][dstoff + rr * 2048]);
            gload16(gV + (size_t)32 * rr * SEQ + s0n,   &ldsV[buf][dstoff + rr * 2048]);
        }
    };

    // Q fragments (A-layout)
    short8 aQ0, aQ1;
    {
        const unsigned short* qp = QKV + (baseRow + q0 + ln) * LDQ + h * HD + quad * 8;
        aQ0 = *(const short8*)(qp);
        aQ1 = *(const short8*)(qp + 32);
    }

    float lsum[4] = {0.f, 0.f, 0.f, 0.f};
    f32x4 o[4];
    for (int nt = 0; nt < 4; ++nt) o[nt] = f32x4{0, 0, 0, 0};

    const float c_exp = 0.1803368802f;    // 0.125 * log2(e)
    unsigned short* pb = &pbuf[wave][0];

    auto computeStep = [&](int s0, int buf, bool partial) {
        const unsigned short* Kb = ldsK[buf];
        const unsigned short* Vf = ldsV[buf];
#pragma unroll
        for (int c = 0; c < 4; ++c) {
            int kbase = s0 + c * 16;
            // pbuf write target: row = quad*4+r, col chunk = c*2+(ln>>3),
            // swizzled by row&7, sub-col = ln&7
            if (partial && kbase > q0 + 15) {   // fully masked tile: zero P
#pragma unroll
                for (int r = 0; r < 4; ++r) {
                    int row = quad * 4 + r;
                    pb[row * 64 + (((c * 2 + (ln >> 3)) ^ (row & 7)) * 8) + (ln & 7)] = 0;
                }
                continue;
            }
            short8 k0f = *(const short8*)&Kb[(c * 16 + ln) * 64 + ((quad ^ (ln & 7)) * 8)];
            short8 k1f = *(const short8*)&Kb[(c * 16 + ln) * 64 + (((4 + quad) ^ (ln & 7)) * 8)];
            f32x4 s = {0, 0, 0, 0};
            s = __builtin_amdgcn_mfma_f32_16x16x32_bf16(aQ0, k0f, s, 0, 0, 0);
            s = __builtin_amdgcn_mfma_f32_16x16x32_bf16(aQ1, k1f, s, 0, 0, 0);
            bool diag = partial && (kbase + 15 > q0);
#pragma unroll
            for (int r = 0; r < 4; ++r) {
                float e = __builtin_exp2f(s[r] * c_exp);
                if (diag && (kbase + ln > q0 + quad * 4 + r)) e = 0.f;  // causal
                lsum[r] += e;
                int row = quad * 4 + r;
                pb[row * 64 + (((c * 2 + (ln >> 3)) ^ (row & 7)) * 8) + (ln & 7)] =
                    (unsigned short)(__float_as_uint(e) >> 16);        // bf16 trunc
            }
        }
        short8 aP0 = *(const short8*)&pb[ln * 64 + ((quad ^ (ln & 7)) * 8)];
        short8 aP1 = *(const short8*)&pb[ln * 64 + (((4 + quad) ^ (ln & 7)) * 8)];
#pragma unroll
        for (int nt = 0; nt < 4; ++nt) {
            short8 v0 = *(const short8*)&Vf[(nt * 16 + ln) * 64 + ((quad ^ (ln & 7)) * 8)];
            short8 v1 = *(const short8*)&Vf[(nt * 16 + ln) * 64 + (((4 + quad) ^ (ln & 7)) * 8)];
            o[nt] = __builtin_amdgcn_mfma_f32_16x16x32_bf16(aP0, v0, o[nt], 0, 0, 0);
            o[nt] = __builtin_amdgcn_mfma_f32_16x16x32_bf16(aP1, v1, o[nt], 0, 0, 0);
        }
    };

    stageKV(0, 0);
    for (int it = 0; it < jg; ++it) {          // full steps, mask-free
        __syncthreads();
        stageKV((it + 1) * 64, (it + 1) & 1);
        computeStep(it * 64, it & 1, false);
    }
    __syncthreads();
    computeStep(jg * 64, jg & 1, true);        // the one partial step

    // epilogue: reduce l across the 16 lanes of each quad, then Y = O / l
    for (int off = 1; off < 16; off <<= 1)
#pragma unroll
        for (int r = 0; r < 4; ++r) lsum[r] += __shfl_xor(lsum[r], off);
#pragma unroll
    for (int r = 0; r < 4; ++r) {
        float inv = 1.0f / lsum[r];
        int t_idx = q0 + quad * 4 + r;
        unsigned short* yp = Y + (baseRow + t_idx) * DM + h * HD + ln;
        for (int nt = 0; nt < 4; ++nt)
            yp[nt * 16] = f2bf(o[nt][r] * inv);
    }
}

extern "C" void kernel_launch(void* const* d_in, const int* in_sizes, int n_in,
                              void* d_out, int out_size, void* d_ws, size_t ws_size,
                              hipStream_t stream) {
    const float* x  = (const float*)d_in[0];
    const float* Wq = (const float*)d_in[1];
    const float* Wk = (const float*)d_in[2];
    const float* Wv = (const float*)d_in[3];
    const float* Wo = (const float*)d_in[4];
    float* out = (float*)d_out;

    char* ws = (char*)d_ws;
    // workspace (22.8 MB): slot0 is xb until qkv-gemm completes, then y.
    unsigned short* xb  = (unsigned short*)(ws);                // 4096x1024 bf16 (8 MB)
    unsigned short* y   = (unsigned short*)(ws);                // alias: attn out
    unsigned short* wtq = (unsigned short*)(ws + 8388608);      // 1152x1024 bf16
    unsigned short* wot = (unsigned short*)(ws + 10747904);     // 1024x1024 bf16
    unsigned short* qkv = (unsigned short*)(ws + 12845056);     // 4096x1152 bf16
    unsigned short* Vt  = (unsigned short*)(ws + 22282240);     // 2x64x2048 bf16 (0.5 MB)

    const int BT = BATCH * SEQ;  // 4096 rows

    hipLaunchKernelGGL(cast_x_kernel, dim3(BT * DM / 4 / 256), dim3(256), 0, stream,
                       x, xb, BT * DM);
    hipLaunchKernelGGL(prep_w_kernel, dim3(DM / 32, DM / 32, 4), dim3(256), 0, stream,
                       Wq, Wk, Wv, Wo, wtq, wot);

    // QKV = x @ [Wq|Wk|Wv] -> bf16; V block also written transposed to Vt
    hipLaunchKernelGGL(gemm_bt_kernel, dim3(LDQ / 64, BT / 64), dim3(256), 0, stream,
                       xb, wtq, (void*)qkv, Vt, BT, LDQ, DM, 1);

    // flash attention (64-key dbuf steps) -> y bf16 (overwrites xb, now dead)
    hipLaunchKernelGGL(attn_kernel, dim3(32 * 32), dim3(256), 0, stream,
                       qkv, Vt, y);

    // out = y @ Wo -> fp32
    hipLaunchKernelGGL(gemm_bt_kernel, dim3(DM / 64, BT / 64), dim3(256), 0, stream,
                       y, wot, (void*)out, nullptr, BT, DM, DM, 0);
}